// Round 1
// baseline (3816.600 us; speedup 1.0000x reference)
//
#include <hip/hip_runtime.h>
#include <hip/hip_bf16.h>

#define DEV_INLINE __device__ __forceinline__

// Problem constants
static constexpr int HN     = 128;   // heads
static constexpr int QLORA  = 1536;
static constexpr int KVL    = 512;   // kv lora rank (= nope attn dim = v dim of MLA)
static constexpr int RD     = 64;    // rope dim
static constexpr int NOPE_  = 128;
static constexpr int VD_    = 128;
static constexpr int HID_   = 5120;
static constexpr int QHD_   = 192;   // NOPE + ROPE
static constexpr int QL     = 512;   // q_len
static constexpr int KVLEN_ = 2048;  // kv_len
static constexpr int DQK    = 576;   // 512 + 64: MLA attention head_dim

typedef float  f32x4 __attribute__((ext_vector_type(4)));
typedef __bf16 bf16x8 __attribute__((ext_vector_type(8)));
typedef unsigned short u16x8 __attribute__((ext_vector_type(8)));

DEV_INLINE unsigned short f2b(float f) {          // fp32 -> bf16 RNE
    union { float f; unsigned u; } v; v.f = f;
    unsigned u = v.u;
    unsigned r = u + 0x7FFFu + ((u >> 16) & 1u);
    return (unsigned short)(r >> 16);
}
DEV_INLINE float b2f(unsigned short h) {
    union { unsigned u; float f; } v; v.u = ((unsigned)h) << 16;
    return v.f;
}

// ---------------------------------------------------------------------------
// small conversion / transpose kernels
// ---------------------------------------------------------------------------

// Kb[k][d] = bf16(compressed_kv[k][d]), (2048 x 576)
__global__ void convert_kb_kern(const float* __restrict__ src, unsigned short* __restrict__ dst) {
    int i = (blockIdx.x * 256 + threadIdx.x) * 4;
    if (i >= KVLEN_ * DQK) return;
    float4 v = *reinterpret_cast<const float4*>(src + i);
    ushort4 o = { f2b(v.x), f2b(v.y), f2b(v.z), f2b(v.w) };
    *reinterpret_cast<ushort4*>(dst + i) = o;
}

// Vt[c][k] = bf16(ckv[k][c])  (512 x 2048), ckv row stride 576
__global__ void transpose_vt_kern(const float* __restrict__ ckv, unsigned short* __restrict__ Vt) {
    __shared__ float t[32][33];
    int k0 = blockIdx.x * 32, c0 = blockIdx.y * 32;
    int tr = threadIdx.x >> 3;          // 0..31
    int tc = (threadIdx.x & 7) * 4;     // 0..28
    float4 v = *reinterpret_cast<const float4*>(ckv + (long)(k0 + tr) * DQK + c0 + tc);
    t[tr][tc + 0] = v.x; t[tr][tc + 1] = v.y; t[tr][tc + 2] = v.z; t[tr][tc + 3] = v.w;
    __syncthreads();
    ushort4 o = { f2b(t[tc + 0][tr]), f2b(t[tc + 1][tr]), f2b(t[tc + 2][tr]), f2b(t[tc + 3][tr]) };
    *reinterpret_cast<ushort4*>(Vt + (long)(c0 + tr) * KVLEN_ + k0 + tc) = o;
}

// qabsT[h][k][d] = bf16(Wkvb[h*256 + d][k]),  (H,512,128)
__global__ void transpose_qabs_kern(const float* __restrict__ Wkvb, unsigned short* __restrict__ qabsT) {
    __shared__ float t[32][33];
    int k0 = blockIdx.x * 32, d0 = blockIdx.y * 32, h = blockIdx.z;
    int tr = threadIdx.x >> 3;
    int tc = (threadIdx.x & 7) * 4;
    float4 v = *reinterpret_cast<const float4*>(Wkvb + ((long)h * 256 + d0 + tr) * KVL + k0 + tc);
    t[tr][tc + 0] = v.x; t[tr][tc + 1] = v.y; t[tr][tc + 2] = v.z; t[tr][tc + 3] = v.w;
    __syncthreads();
    ushort4 o = { f2b(t[tc + 0][tr]), f2b(t[tc + 1][tr]), f2b(t[tc + 2][tr]), f2b(t[tc + 3][tr]) };
    *reinterpret_cast<ushort4*>(qabsT + ((long)h * KVL + k0 + tr) * NOPE_ + d0 + tc) = o;
}

// ---------------------------------------------------------------------------
// RMSNorm: qn[row] = bf16( w * x * rsqrt(mean(x^2)+eps) ), row len 1536
// ---------------------------------------------------------------------------
__global__ __launch_bounds__(256) void rmsnorm_kern(const float* __restrict__ X,
                                                    const float* __restrict__ w,
                                                    unsigned short* __restrict__ Y) {
    int row = blockIdx.x;
    const float* x = X + (long)row * QLORA;
    float ss = 0.f;
    for (int j = threadIdx.x; j < QLORA; j += 256) { float v = x[j]; ss += v * v; }
    #pragma unroll
    for (int m = 1; m < 64; m <<= 1) ss += __shfl_xor(ss, m);
    __shared__ float red[4];
    if ((threadIdx.x & 63) == 0) red[threadIdx.x >> 6] = ss;
    __syncthreads();
    float rs = rsqrtf((red[0] + red[1] + red[2] + red[3]) * (1.0f / QLORA) + 1e-6f);
    unsigned short* y = Y + (long)row * QLORA;
    for (int j = threadIdx.x; j < QLORA; j += 256) y[j] = f2b(w[j] * x[j] * rs);
}

// ---------------------------------------------------------------------------
// RoPE on q_pe: reads Cq[h][q][128+..191], writes Qb[h][q][512..575]
// out[i]    = x_{2i} c_i - x_{2i+1} s_i
// out[32+i] = x_{2i+1} c_i + x_{2i} s_i,   c_i = cos(pos * 10000^(-i/32))
// ---------------------------------------------------------------------------
__global__ void rope_kern(const unsigned short* __restrict__ Cq,
                          const int* __restrict__ pos,
                          unsigned short* __restrict__ Qb) {
    int idx = blockIdx.x * 256 + threadIdx.x;     // H*QL*32 total
    if (idx >= HN * QL * 32) return;
    int i = idx & 31;
    int q = (idx >> 5) & (QL - 1);
    int h = idx >> 14;
    long cbase = ((long)h * QL + q) * QHD_ + 128;
    float x0 = b2f(Cq[cbase + 2 * i]);
    float x1 = b2f(Cq[cbase + 2 * i + 1]);
    float invf = expf(-((float)i / 32.0f) * 9.210340371976184f);  // ln(10000)
    float f = (float)pos[q] * invf;
    float sn, cs;
    sincosf(f, &sn, &cs);
    long qb = ((long)h * QL + q) * DQK + KVL;
    Qb[qb + i]      = f2b(x0 * cs - x1 * sn);
    Qb[qb + 32 + i] = f2b(x1 * cs + x0 * sn);
}

// ---------------------------------------------------------------------------
// Generic GEMM: C(M,N) = A(M,K) @ B(N,K)^T, batched via grid.z.
// A: f32 or bf16(u16), B: f32 or bf16, C: f32 or bf16. 128x128 tile, BK=32,
// double-buffered LDS, 4 waves each computing 64x64 via 16 mfma_16x16x32_bf16.
// M must be a multiple of 128, K a multiple of 32; N guarded.
// ---------------------------------------------------------------------------
DEV_INLINE void storeC(float* p, float v) { *p = v; }
DEV_INLINE void storeC(unsigned short* p, float v) { *p = f2b(v); }

template <typename T>
DEV_INLINE void load8_bf16(const T* src, unsigned short* dst) {
    if constexpr (sizeof(T) == 4) {
        const float4* s = reinterpret_cast<const float4*>(src);
        float4 a = s[0], b = s[1];
        dst[0] = f2b(a.x); dst[1] = f2b(a.y); dst[2] = f2b(a.z); dst[3] = f2b(a.w);
        dst[4] = f2b(b.x); dst[5] = f2b(b.y); dst[6] = f2b(b.z); dst[7] = f2b(b.w);
    } else {
        u16x8 v = *reinterpret_cast<const u16x8*>(src);
        #pragma unroll
        for (int j = 0; j < 8; ++j) dst[j] = v[j];
    }
}

template <typename TA, typename TB, typename TC>
__global__ __launch_bounds__(256, 2) void gemm_bt_kern(
    const TA* __restrict__ A, const TB* __restrict__ B, TC* __restrict__ C,
    int M, int N, int K, int lda, int ldb, int ldc,
    long sA, long sB, long sC) {
    __shared__ unsigned short As[2][128][40];   // pad 32->40: conflict-free + 16B aligned
    __shared__ unsigned short Bs[2][128][40];
    const int tid = threadIdx.x;
    const int m0 = blockIdx.x * 128, n0 = blockIdx.y * 128;
    A += (long)blockIdx.z * sA;
    B += (long)blockIdx.z * sB;
    C += (long)blockIdx.z * sC;
    const int l = tid & 63, w = tid >> 6;
    const int wm = w >> 1, wn = w & 1;
    const int lr = l & 15, lh = l >> 4;
    const int srow = tid >> 2;           // 0..63
    const int scol = (tid & 3) * 8;      // 0,8,16,24
    const int nk = K / 32;

    f32x4 acc[4][4];
    #pragma unroll
    for (int i = 0; i < 4; ++i)
        #pragma unroll
        for (int j = 0; j < 4; ++j) acc[i][j] = f32x4{0.f, 0.f, 0.f, 0.f};

    auto stage = [&](int buf, int kt) {
        int k0 = kt * 32;
        #pragma unroll
        for (int rr = 0; rr < 2; ++rr) {
            int row = srow + rr * 64;
            {
                unsigned short tmp[8];
                load8_bf16(A + (long)(m0 + row) * lda + k0 + scol, tmp);
                u16x8 vv;
                #pragma unroll
                for (int j = 0; j < 8; ++j) vv[j] = tmp[j];
                *reinterpret_cast<u16x8*>(&As[buf][row][scol]) = vv;
            }
            {
                unsigned short tmp[8] = {0, 0, 0, 0, 0, 0, 0, 0};
                int grow = n0 + row;
                if (grow < N) load8_bf16(B + (long)grow * ldb + k0 + scol, tmp);
                u16x8 vv;
                #pragma unroll
                for (int j = 0; j < 8; ++j) vv[j] = tmp[j];
                *reinterpret_cast<u16x8*>(&Bs[buf][row][scol]) = vv;
            }
        }
    };

    stage(0, 0);
    __syncthreads();
    for (int kt = 0; kt < nk; ++kt) {
        int cur = kt & 1;
        if (kt + 1 < nk) stage(cur ^ 1, kt + 1);
        bf16x8 af[4], bf_[4];
        #pragma unroll
        for (int mt = 0; mt < 4; ++mt)
            af[mt] = *reinterpret_cast<const bf16x8*>(&As[cur][wm * 64 + mt * 16 + lr][lh * 8]);
        #pragma unroll
        for (int nt = 0; nt < 4; ++nt)
            bf_[nt] = *reinterpret_cast<const bf16x8*>(&Bs[cur][wn * 64 + nt * 16 + lr][lh * 8]);
        #pragma unroll
        for (int mt = 0; mt < 4; ++mt)
            #pragma unroll
            for (int nt = 0; nt < 4; ++nt)
                acc[mt][nt] = __builtin_amdgcn_mfma_f32_16x16x32_bf16(af[mt], bf_[nt], acc[mt][nt], 0, 0, 0);
        __syncthreads();
    }

    // C/D layout (m89-verified): col = lane&15, row = (lane>>4)*4 + reg
    #pragma unroll
    for (int mt = 0; mt < 4; ++mt)
        #pragma unroll
        for (int nt = 0; nt < 4; ++nt) {
            int n = n0 + wn * 64 + nt * 16 + lr;
            if (n < N) {
                #pragma unroll
                for (int r = 0; r < 4; ++r) {
                    int m = m0 + wm * 64 + mt * 16 + lh * 4 + r;
                    storeC(&C[(long)m * ldc + n], acc[mt][nt][r]);
                }
            }
        }
}

// ---------------------------------------------------------------------------
// Flash attention (MLA): per wg = (head, 64 q rows); 4 waves x 16 q rows.
// Q[h] (512x576) bf16, Kb (2048x576) bf16, Vt (512x2048) bf16 -> O1[h] 512x512
// kv tiles of 64, online softmax, PV via Vt (contiguous B-fragments).
// ---------------------------------------------------------------------------
__global__ __launch_bounds__(256, 1) void flash_attn_kern(
    const unsigned short* __restrict__ Qb,
    const unsigned short* __restrict__ Kb,
    const unsigned short* __restrict__ Vt,
    unsigned short* __restrict__ O1) {
    __shared__ unsigned short Kt[64][584];   // 64 kv rows x 576 d (pad->584; 1168B rows, 16B-aligned)
    __shared__ unsigned short Vl[512][72];   // 512 v rows x 64 kv (pad->72; 144B rows)
    __shared__ unsigned short Pl[4][16][72]; // per-wave P: 16 q x 64 kv
    const int tid = threadIdx.x;
    const int h = blockIdx.y;
    const int q0 = blockIdx.x * 64;
    const int l = tid & 63, w = tid >> 6;
    const int lr = l & 15, lh = l >> 4;

    // Q fragments resident in registers (18 k-blocks of 32)
    bf16x8 aq[18];
    {
        const unsigned short* qp = Qb + ((long)h * QL + q0 + w * 16 + lr) * DQK + lh * 8;
        #pragma unroll
        for (int ks = 0; ks < 18; ++ks)
            aq[ks] = *reinterpret_cast<const bf16x8*>(qp + ks * 32);
    }

    f32x4 acc[32];
    #pragma unroll
    for (int vt = 0; vt < 32; ++vt) acc[vt] = f32x4{0.f, 0.f, 0.f, 0.f};
    float mrow[4] = {-1e30f, -1e30f, -1e30f, -1e30f};
    float lrow[4] = {0.f, 0.f, 0.f, 0.f};
    const float scale = 0.07216878364870322f;   // rsqrt(192)

    for (int kt = 0; kt < KVLEN_ / 64; ++kt) {
        // stage K tile (64 x 576 = 4608 x 16B chunks)
        #pragma unroll
        for (int i = 0; i < 18; ++i) {
            int id = i * 256 + tid;
            int row = id / 72, c16 = id % 72;
            *reinterpret_cast<u16x8*>(&Kt[row][c16 * 8]) =
                *reinterpret_cast<const u16x8*>(Kb + (long)(kt * 64 + row) * DQK + c16 * 8);
        }
        // stage V^T tile (512 x 64 = 4096 x 16B chunks)
        #pragma unroll
        for (int i = 0; i < 16; ++i) {
            int id = i * 256 + tid;
            int row = id >> 3, c16 = id & 7;
            *reinterpret_cast<u16x8*>(&Vl[row][c16 * 8]) =
                *reinterpret_cast<const u16x8*>(Vt + (long)row * KVLEN_ + kt * 64 + c16 * 8);
        }
        __syncthreads();

        // S = Q @ K^T  (16 q x 64 kv per wave)
        f32x4 s[4];
        #pragma unroll
        for (int nt = 0; nt < 4; ++nt) s[nt] = f32x4{0.f, 0.f, 0.f, 0.f};
        #pragma unroll
        for (int ks = 0; ks < 18; ++ks) {
            #pragma unroll
            for (int nt = 0; nt < 4; ++nt) {
                bf16x8 bk = *reinterpret_cast<const bf16x8*>(&Kt[nt * 16 + lr][ks * 32 + lh * 8]);
                s[nt] = __builtin_amdgcn_mfma_f32_16x16x32_bf16(aq[ks], bk, s[nt], 0, 0, 0);
            }
        }
        #pragma unroll
        for (int nt = 0; nt < 4; ++nt) s[nt] *= scale;

        // online softmax; lane holds rows lh*4+r, cols nt*16+lr
        float tmax[4], corr[4], psum[4];
        #pragma unroll
        for (int r = 0; r < 4; ++r) {
            tmax[r] = fmaxf(fmaxf(s[0][r], s[1][r]), fmaxf(s[2][r], s[3][r]));
            #pragma unroll
            for (int m = 1; m < 16; m <<= 1) tmax[r] = fmaxf(tmax[r], __shfl_xor(tmax[r], m));
            float mnew = fmaxf(mrow[r], tmax[r]);
            corr[r] = __expf(mrow[r] - mnew);
            mrow[r] = mnew;
            psum[r] = 0.f;
        }
        #pragma unroll
        for (int nt = 0; nt < 4; ++nt)
            #pragma unroll
            for (int r = 0; r < 4; ++r) {
                float p = __expf(s[nt][r] - mrow[r]);
                s[nt][r] = p;
                psum[r] += p;
            }
        #pragma unroll
        for (int r = 0; r < 4; ++r) {
            #pragma unroll
            for (int m = 1; m < 16; m <<= 1) psum[r] += __shfl_xor(psum[r], m);
            lrow[r] = lrow[r] * corr[r] + psum[r];
        }
        #pragma unroll
        for (int vt = 0; vt < 32; ++vt) {
            acc[vt][0] *= corr[0]; acc[vt][1] *= corr[1];
            acc[vt][2] *= corr[2]; acc[vt][3] *= corr[3];
        }
        // write P (bf16) for this wave
        #pragma unroll
        for (int nt = 0; nt < 4; ++nt)
            #pragma unroll
            for (int r = 0; r < 4; ++r)
                Pl[w][lh * 4 + r][nt * 16 + lr] = f2b(s[nt][r]);
        // same-wave DS ops are in-order: reads below see writes above

        // O += P @ V  via Vt tile (B-fragments contiguous)
        #pragma unroll
        for (int ks2 = 0; ks2 < 2; ++ks2) {
            bf16x8 ap = *reinterpret_cast<const bf16x8*>(&Pl[w][lr][ks2 * 32 + lh * 8]);
            #pragma unroll
            for (int vt = 0; vt < 32; ++vt) {
                bf16x8 bv = *reinterpret_cast<const bf16x8*>(&Vl[vt * 16 + lr][ks2 * 32 + lh * 8]);
                acc[vt] = __builtin_amdgcn_mfma_f32_16x16x32_bf16(ap, bv, acc[vt], 0, 0, 0);
            }
        }
        __syncthreads();
    }

    // epilogue: O1[h][q][v] = acc / l
    #pragma unroll
    for (int vt = 0; vt < 32; ++vt)
        #pragma unroll
        for (int r = 0; r < 4; ++r) {
            long q = q0 + w * 16 + lh * 4 + r;
            O1[((long)h * QL + q) * KVL + vt * 16 + lr] = f2b(acc[vt][r] / lrow[r]);
        }
}

// ---------------------------------------------------------------------------
// launcher
// ---------------------------------------------------------------------------
extern "C" void kernel_launch(void* const* d_in, const int* in_sizes, int n_in,
                              void* d_out, int out_size, void* d_ws, size_t ws_size,
                              hipStream_t stream) {
    (void)in_sizes; (void)n_in; (void)out_size;
    const float* hidden = (const float*)d_in[0];
    const int*   pos    = (const int*)d_in[1];
    const float* ckv    = (const float*)d_in[2];
    const float* Wqa    = (const float*)d_in[3];
    const float* lnw    = (const float*)d_in[4];
    const float* Wqb    = (const float*)d_in[5];
    const float* Wkvb   = (const float*)d_in[6];
    const float* Wo     = (const float*)d_in[7];
    float* out = (float*)d_out;

    char* ws = (char*)d_ws;
    // Region A: O1 (written at flash time) aliases the early temporaries
    // (qlat, qn, Cq, qabsT — all dead before flash runs).
    unsigned short* O1    = (unsigned short*)(ws);                       // 67,108,864 B
    float*          qlat  = (float*)(ws + 0);                            //  3,145,728
    unsigned short* qn    = (unsigned short*)(ws + 3145728);             //  1,572,864
    unsigned short* Cq    = (unsigned short*)(ws + 4718592);             // 25,165,824
    unsigned short* qabsT = (unsigned short*)(ws + 29884416);            // 16,777,216 (end 46.7MB < 67MB)
    unsigned short* Qb    = (unsigned short*)(ws + 67108864);            // 75,497,472
    unsigned short* Kbuf  = (unsigned short*)(ws + 142606336);           //  2,359,296
    unsigned short* Vt    = (unsigned short*)(ws + 144965632);           //  2,097,152
    unsigned short* O2    = (unsigned short*)(ws + 147062784);           // 16,777,216 -> end 163,840,000
    if (ws_size < 163840000UL) return;  // workspace too small: leave output poisoned (visible failure)

    // conversions / transposes
    convert_kb_kern<<<(KVLEN_ * DQK / 4 + 255) / 256, 256, 0, stream>>>(ckv, Kbuf);
    transpose_vt_kern<<<dim3(KVLEN_ / 32, KVL / 32), 256, 0, stream>>>(ckv, Vt);
    transpose_qabs_kern<<<dim3(KVL / 32, NOPE_ / 32, HN), 256, 0, stream>>>(Wkvb, qabsT);

    // q_lat = hidden @ Wqa^T  (512x1536, K=5120)
    gemm_bt_kern<float, float, float><<<dim3(QL / 128, QLORA / 128, 1), 256, 0, stream>>>(
        hidden, Wqa, qlat, QL, QLORA, HID_, HID_, HID_, QLORA, 0, 0, 0);
    rmsnorm_kern<<<QL, 256, 0, stream>>>(qlat, lnw, qn);

    // per-head: Cq[h] = qn @ Wqb[h]^T  (512x192, K=1536)
    gemm_bt_kern<unsigned short, float, unsigned short><<<dim3(QL / 128, 2, HN), 256, 0, stream>>>(
        qn, Wqb, Cq, QL, QHD_, QLORA, QLORA, QLORA, QHD_, 0, (long)QHD_ * QLORA, (long)QL * QHD_);

    // rope: Cq[.,128:192] -> Qb[.,512:576]
    rope_kern<<<(HN * QL * 32 + 255) / 256, 256, 0, stream>>>(Cq, pos, Qb);

    // per-head: Qb[h][:, :512] = Cq[h][:, :128] @ qabsT[h]  (512x512, K=128)
    gemm_bt_kern<unsigned short, unsigned short, unsigned short><<<dim3(QL / 128, KVL / 128, HN), 256, 0, stream>>>(
        Cq, qabsT, Qb, QL, KVL, NOPE_, QHD_, NOPE_, DQK,
        (long)QL * QHD_, (long)KVL * NOPE_, (long)QL * DQK);

    // flash attention -> O1 (H,512,512)
    flash_attn_kern<<<dim3(QL / 64, HN), 256, 0, stream>>>(Qb, Kbuf, Vt, O1);

    // per-head: O2[:, h*128:+128] = O1[h] @ out_absorb[h]^T  (512x128, K=512)
    gemm_bt_kern<unsigned short, float, unsigned short><<<dim3(QL / 128, 1, HN), 256, 0, stream>>>(
        O1, Wkvb + (long)NOPE_ * KVL, O2, QL, VD_, KVL, KVL, KVL, HN * VD_,
        (long)QL * KVL, (long)256 * KVL, (long)VD_);

    // out = O2 @ Wo^T  (512x5120, K=16384)
    gemm_bt_kern<unsigned short, float, float><<<dim3(QL / 128, HID_ / 128, 1), 256, 0, stream>>>(
        O2, Wo, out, QL, HID_, HN * VD_, HN * VD_, HN * VD_, HID_, 0, 0, 0);
}